// Round 25
// baseline (590.324 us; speedup 1.0000x reference)
//
#include <hip/hip_runtime.h>

typedef float f16v __attribute__((ext_vector_type(16)));
typedef float f4 __attribute__((ext_vector_type(4)));
typedef float f2 __attribute__((ext_vector_type(2)));

// static_for with FRONTEND-constant indices (SSA, no alloca) — see R6 notes.
template<int I> struct ic { static constexpr int v = I; };
template<int... I> struct iseq {};
template<int N, int... I> struct mk : mk<N-1, N-1, I...> {};
template<int... I> struct mk<0, I...> { using t = iseq<I...>; };
template<class F, int... I>
__device__ __forceinline__ void sfor_impl(F f, iseq<I...>) { (f(ic<I>{}), ...); }
template<int N, class F>
__device__ __forceinline__ void sfor(F f) { sfor_impl(f, typename mk<N>::t{}); }

namespace {
constexpr float kSigma  = 1.2f;    // 2*l2_reg + rho
constexpr float kJitter = 1e-5f;
constexpr int   kIters  = 100;
constexpr int   MD = 16;
constexpr int   ND = 32;
constexpr int   SPA = 4;     // samples per 128-thread block (32 lanes each)
constexpr int   AS  = 132;   // A sample stride in float4 (528 floats)
}

__device__ __forceinline__ float4 lds_a4(const float* As, int r, int j) {
    return *reinterpret_cast<const float4*>(&As[r * 32 + ((j ^ (r & 7)) << 2)]);
}
__device__ __forceinline__ float lds_a(const float* As, int r, int n) {
    return As[r * 32 + ((((n >> 2) ^ (r & 7)) << 2) | (n & 3))];
}

// === Fused: 32 lanes/sample, 1 P-row/lane (32 regs, NATURAL order), LDS s-broadcast ===
// Engine matrix from R15-R24: DPP fmac ~6cyc (rate cap 155us, R19); LDS-broadcast +
// full-rate FMA is faster IFF P stays in arch VGPRs; parking kicks in at >=64 P regs
// (R15/R16/R19) but 32 scalars stay arch (R21: VGPR 44, occ 50%). This kernel is the
// unexplored cell: 1 row/lane (8 f4 = 32 regs) + plain v_fma + s-exchange through the
// sample's dead A-region. Per iter: 1 ds_write (2-way banks, free) + 8 uniform b128
// reads (2 distinct addrs/instr) + 32 full-rate fma. No ring, no DPP, no asm.
__global__ void __launch_bounds__(128)
admm_fused_kernel(const float* __restrict__ Ag, const float* __restrict__ bg,
                  const float* __restrict__ cg, const float* __restrict__ lbg,
                  const float* __restrict__ ubg, float* __restrict__ outg)
{
    __shared__ __align__(16) float A_lds[SPA * AS * 4];   // 8448 B (only LDS)

    const int t = threadIdx.x;

    // ---- stage A for the block's 4 samples (coalesced, xor-swizzled f4)
    {
        const float4* src = reinterpret_cast<const float4*>(Ag) +
                            (size_t)blockIdx.x * (SPA * MD * ND / 4);
        float4* dst = reinterpret_cast<float4*>(A_lds);
        #pragma unroll
        for (int r = 0; r < 4; ++r) {               // 512 f4 / 128 threads
            int idx = r * 128 + t;
            int smp = idx >> 7;
            int row = (idx >> 3) & 15;
            int j   = idx & 7;
            dst[smp * AS + row * 8 + (j ^ (row & 7))] = src[idx];
        }
    }
    __syncthreads();   // only barrier

    const int lane = t & 63;
    const int l    = lane & 31;                     // P-row / variable owned by this lane
    const int lr   = l & 15;                        // M-row (duplicated in upper half)
    const int smp  = (t >> 6) * 2 + (lane >> 5);
    const size_t gs = (size_t)blockIdx.x * SPA + smp;
    const float* As = &A_lds[smp * AS * 4];

    // ---- A row lr into registers (M build; dup across halves) — R21-proven phase 1
    f16v Ar0, Ar1;
    sfor<4>([&](auto J) {
        constexpr int j = decltype(J)::v;
        float4 v  = lds_a4(As, lr, j);
        Ar0[4*j+0] = v.x;  Ar0[4*j+1] = v.y;  Ar0[4*j+2] = v.z;  Ar0[4*j+3] = v.w;
        float4 w4 = lds_a4(As, lr, j + 4);
        Ar1[4*j+0] = w4.x; Ar1[4*j+1] = w4.y; Ar1[4*j+2] = w4.z; Ar1[4*j+3] = w4.w;
    });

    f16v Mrow, Vrow;
    sfor<16>([&](auto K) {
        constexpr int k = decltype(K)::v;
        float a0 = 0.f, a1 = 0.f, a2 = 0.f, a3 = 0.f;
        sfor<4>([&](auto J) {
            constexpr int j = decltype(J)::v;
            float4 v  = lds_a4(As, k, j);
            a0 += Ar0[4*j+0]*v.x;  a1 += Ar0[4*j+1]*v.y;
            a2 += Ar0[4*j+2]*v.z;  a3 += Ar0[4*j+3]*v.w;
            float4 w4 = lds_a4(As, k, j + 4);
            a0 += Ar1[4*j+0]*w4.x; a1 += Ar1[4*j+1]*w4.y;
            a2 += Ar1[4*j+2]*w4.z; a3 += Ar1[4*j+3]*w4.w;
        });
        Mrow[k] = (a0+a1)+(a2+a3) + ((k == lr) ? kJitter : 0.f);
        Vrow[k] = (k == lr) ? 1.f : 0.f;
    });

    // ---- triangular Gauss-Jordan (SPD), width-32 shuffles, lr-duplicated
    sfor<16>([&](auto K) {
        constexpr int k = decltype(K)::v;
        float ip = 1.f / __shfl(Mrow[k], k, 32);
        float f  = (lr == k) ? 0.f : Mrow[k] * ip;
        sfor<16>([&](auto J) {
            constexpr int j = decltype(J)::v;
            if constexpr (j > k) {
                float mj = __shfl(Mrow[j], k, 32);
                Mrow[j] = (lr == k) ? mj * ip : Mrow[j] - f * mj;
            }
        });
        sfor<16>([&](auto J) {
            constexpr int j = decltype(J)::v;
            if constexpr (j < k) {
                float vj = __shfl(Vrow[j], k, 32);
                Vrow[j] = (lr == k) ? vj * ip : Vrow[j] - f * vj;
            }
        });
        Vrow[k] = (lr == k) ? ip : -f;
    });

    // ---- w = Minv b (lane holds w[lr], dup)
    float w = 0.f;
    {
        float bval = bg[gs * MD + lr];
        sfor<16>([&](auto K) {
            constexpr int k = decltype(K)::v;
            w += Vrow[k] * __shfl(bval, k, 32);
        });
    }

    // ---- C row l of A^T Minv (16 floats) + q = (A^T w)[l]
    f16v C = (f16v)0.0f;
    float q = 0.f;
    sfor<16>([&](auto K) {
        constexpr int k = decltype(K)::v;
        float a = lds_a(As, k, l);
        q = fmaf(a, __shfl(w, k, 32), q);
        sfor<16>([&](auto M) {
            constexpr int m = decltype(M)::v;
            C[m] = fmaf(a, __shfl(Vrow[m], k, 32), C[m]);
        });
    });

    // ---- P row l in NATURAL column order: Q_k = P[l][4k..4k+3], 8 f4 = 32 regs.
    // Accumulate C[m] * A[m][*] via uniform f4 row-reads (broadcast within group).
    f4 Q0=(f4)0.f, Q1=(f4)0.f, Q2=(f4)0.f, Q3=(f4)0.f,
       Q4=(f4)0.f, Q5=(f4)0.f, Q6=(f4)0.f, Q7=(f4)0.f;
    sfor<16>([&](auto M) {
        constexpr int m = decltype(M)::v;
        float cm = C[m];
        float4 v;
        v = lds_a4(As, m, 0);
        Q0[0]=fmaf(cm,v.x,Q0[0]); Q0[1]=fmaf(cm,v.y,Q0[1]);
        Q0[2]=fmaf(cm,v.z,Q0[2]); Q0[3]=fmaf(cm,v.w,Q0[3]);
        v = lds_a4(As, m, 1);
        Q1[0]=fmaf(cm,v.x,Q1[0]); Q1[1]=fmaf(cm,v.y,Q1[1]);
        Q1[2]=fmaf(cm,v.z,Q1[2]); Q1[3]=fmaf(cm,v.w,Q1[3]);
        v = lds_a4(As, m, 2);
        Q2[0]=fmaf(cm,v.x,Q2[0]); Q2[1]=fmaf(cm,v.y,Q2[1]);
        Q2[2]=fmaf(cm,v.z,Q2[2]); Q2[3]=fmaf(cm,v.w,Q2[3]);
        v = lds_a4(As, m, 3);
        Q3[0]=fmaf(cm,v.x,Q3[0]); Q3[1]=fmaf(cm,v.y,Q3[1]);
        Q3[2]=fmaf(cm,v.z,Q3[2]); Q3[3]=fmaf(cm,v.w,Q3[3]);
        v = lds_a4(As, m, 4);
        Q4[0]=fmaf(cm,v.x,Q4[0]); Q4[1]=fmaf(cm,v.y,Q4[1]);
        Q4[2]=fmaf(cm,v.z,Q4[2]); Q4[3]=fmaf(cm,v.w,Q4[3]);
        v = lds_a4(As, m, 5);
        Q5[0]=fmaf(cm,v.x,Q5[0]); Q5[1]=fmaf(cm,v.y,Q5[1]);
        Q5[2]=fmaf(cm,v.z,Q5[2]); Q5[3]=fmaf(cm,v.w,Q5[3]);
        v = lds_a4(As, m, 6);
        Q6[0]=fmaf(cm,v.x,Q6[0]); Q6[1]=fmaf(cm,v.y,Q6[1]);
        Q6[2]=fmaf(cm,v.z,Q6[2]); Q6[3]=fmaf(cm,v.w,Q6[3]);
        v = lds_a4(As, m, 7);
        Q7[0]=fmaf(cm,v.x,Q7[0]); Q7[1]=fmaf(cm,v.y,Q7[1]);
        Q7[2]=fmaf(cm,v.z,Q7[2]); Q7[3]=fmaf(cm,v.w,Q7[3]);
    });
    // finalize: Q = (I - CA)/sigma; identity at column l
    constexpr float is = 1.f / kSigma;
#define QFIN(K, B) \
    Q##K[0] = ((((B)+0)==l ? 1.f : 0.f) - Q##K[0]) * is; \
    Q##K[1] = ((((B)+1)==l ? 1.f : 0.f) - Q##K[1]) * is; \
    Q##K[2] = ((((B)+2)==l ? 1.f : 0.f) - Q##K[2]) * is; \
    Q##K[3] = ((((B)+3)==l ? 1.f : 0.f) - Q##K[3]) * is;
    QFIN(0,0) QFIN(1,4) QFIN(2,8) QFIN(3,12) QFIN(4,16) QFIN(5,20) QFIN(6,24) QFIN(7,28)
#undef QFIN

    // ---- d = q - P c (c read as uniform f4 global loads, L1/L2 broadcast)
    float d;
    {
        const f4* cq = reinterpret_cast<const f4*>(cg + gs * ND);
        f4 c0 = cq[0], c1 = cq[1], c2 = cq[2], c3 = cq[3];
        f4 c4 = cq[4], c5 = cq[5], c6 = cq[6], c7 = cq[7];
        float p0 = 0.f, p1 = 0.f, p2 = 0.f, p3 = 0.f;
#define DDOT(K, CK) \
        p0 = fmaf(Q##K[0], CK[0], p0); p1 = fmaf(Q##K[1], CK[1], p1); \
        p2 = fmaf(Q##K[2], CK[2], p2); p3 = fmaf(Q##K[3], CK[3], p3);
        DDOT(0,c0) DDOT(1,c1) DDOT(2,c2) DDOT(3,c3)
        DDOT(4,c4) DDOT(5,c5) DDOT(6,c6) DDOT(7,c7)
#undef DDOT
        d = q - ((p0 + p1) + (p2 + p3));
    }

    // ================= Phase 2: 100 iterations, s-exchange in dead A-region =================
    // Sb = own sample's A region (group-private, dead now). Write: wave's 64 lanes hit
    // each bank exactly twice (2-way, free). Reads: uniform f4 per group, 2 distinct
    // addresses per instruction.
    float lb = lbg[gs * ND + l];
    float ub = ubg[gs * ND + l];
    float z  = fminf(fmaxf(0.f, lb), ub);
    float u  = 0.f, x = 0.f;

    float* Sb = const_cast<float*>(As);
    const f4* Sv = reinterpret_cast<const f4*>(Sb);

    for (int it = 0; it < kIters; ++it) {
        float s = z - u;                                   // rho == 1
        Sb[l] = s;
        asm volatile("s_waitcnt lgkmcnt(0)" ::: "memory"); // wave-synchronous exchange
        f4 s0 = Sv[0], s1 = Sv[1], s2 = Sv[2], s3 = Sv[3];
        f4 s4 = Sv[4], s5 = Sv[5], s6 = Sv[6], s7 = Sv[7];
        float a0 = d, a1 = 0.f, a2 = 0.f, a3 = 0.f;        // 4 chains, 8 deep
#define XK(K, SK) \
        a0 = fmaf(Q##K[0], SK[0], a0); a1 = fmaf(Q##K[1], SK[1], a1); \
        a2 = fmaf(Q##K[2], SK[2], a2); a3 = fmaf(Q##K[3], SK[3], a3);
        XK(0,s0) XK(1,s1) XK(2,s2) XK(3,s3) XK(4,s4) XK(5,s5) XK(6,s6) XK(7,s7)
#undef XK
        x = (a0 + a1) + (a2 + a3);
        float tv = x + u;
        z = fminf(fmaxf(tv, lb), ub);
        u = tv - z;
    }

    outg[gs * ND + l] = x;
}

extern "C" void kernel_launch(void* const* d_in, const int* in_sizes, int n_in,
                              void* d_out, int out_size, void* d_ws, size_t ws_size,
                              hipStream_t stream) {
    const float* A  = (const float*)d_in[0];
    const float* b  = (const float*)d_in[1];
    const float* c  = (const float*)d_in[2];
    const float* lb = (const float*)d_in[3];
    const float* ub = (const float*)d_in[4];
    float* out = (float*)d_out;
    const int B = in_sizes[1] / MD;      // 32768 samples
    admm_fused_kernel<<<B / SPA, 128, 0, stream>>>(A, b, c, lb, ub, out);
}

// Round 26
// 155.814 us; speedup vs baseline: 3.7887x; 3.7887x over previous
//
#include <hip/hip_runtime.h>

typedef float f16v __attribute__((ext_vector_type(16)));
typedef float f4 __attribute__((ext_vector_type(4)));
typedef float f2 __attribute__((ext_vector_type(2)));

// static_for with FRONTEND-constant indices (SSA, no alloca) — see R6 notes.
template<int I> struct ic { static constexpr int v = I; };
template<int... I> struct iseq {};
template<int N, int... I> struct mk : mk<N-1, N-1, I...> {};
template<int... I> struct mk<0, I...> { using t = iseq<I...>; };
template<class F, int... I>
__device__ __forceinline__ void sfor_impl(F f, iseq<I...>) { (f(ic<I>{}), ...); }
template<int N, class F>
__device__ __forceinline__ void sfor(F f) { sfor_impl(f, typename mk<N>::t{}); }

namespace {
constexpr float kSigma  = 1.2f;    // 2*l2_reg + rho
constexpr float kJitter = 1e-5f;
constexpr int   kIters  = 100;
constexpr int   MD = 16;
constexpr int   ND = 32;
constexpr int   SPA = 8;     // samples per 128-thread block (16 lanes each)
constexpr int   AS  = 132;   // A sample stride in float4
}

__device__ __forceinline__ float4 lds_a4(const float* As, int r, int j) {
    return *reinterpret_cast<const float4*>(&As[r * 32 + ((j ^ (r & 7)) << 2)]);
}
__device__ __forceinline__ f2 lds_a2(const float* As, int r, int n) {
    return *reinterpret_cast<const f2*>(
        &As[r * 32 + ((((n >> 2) ^ (r & 7)) << 2) | (n & 3))]);
}

// ============ Fused kernel: precompute P (ring order) + 100 LDS-free ADMM iters ============
// MEASURED OPTIMUM (R19: 155.4us, VALUBusy 97%, VGPR 72, zero scratch). All five
// subsequent variants regressed: R21 32-lane DPP (177), R22 interleaved DPP (198),
// R23 bulk-pinned LDS (473), R24 hybrid DPP+LDS (173), R25 natural-order LDS (590).
// Phase 1: build P rows 2l,2l+1 in RING order (slot j = cols 2cp,2cp+1, cp=(l-j)&15);
// Minv hand-off via width-16 shuffles (no LDS buffer -> 16.9KB/block, 9 blocks/CU).
// Phase 2: x = P s via 16-step DPP ring — v_fmac_f32_dpp row_ror:j fuses the lane
// rotation into the FMA: zero LDS, no barriers, no waitcnt in the loop.
__global__ void __launch_bounds__(128)
admm_fused_kernel(const float* __restrict__ Ag, const float* __restrict__ bg,
                  const float* __restrict__ cg, const float* __restrict__ lbg,
                  const float* __restrict__ ubg, float* __restrict__ outg)
{
    __shared__ __align__(16) float A_lds[SPA * AS * 4];   // 16896 B (only LDS)

    const int t = threadIdx.x;

    // ---- stage A for the block's 8 samples (coalesced, xor-swizzled f4)
    {
        const float4* src = reinterpret_cast<const float4*>(Ag) +
                            (size_t)blockIdx.x * (SPA * MD * ND / 4);
        float4* dst = reinterpret_cast<float4*>(A_lds);
        #pragma unroll
        for (int r = 0; r < 8; ++r) {
            int idx = r * 128 + t;
            int smp = idx >> 7;
            int row = (idx >> 3) & 15;
            int j   = idx & 7;
            dst[smp * AS + row * 8 + (j ^ (row & 7))] = src[idx];
        }
    }
    __syncthreads();   // only barrier in the kernel

    const int lane = t & 63;
    const int l    = lane & 15;
    const int n0   = 2 * l;
    const int smp  = (t >> 6) * 4 + (lane >> 4);
    const size_t gs = (size_t)blockIdx.x * SPA + smp;
    const float* As = &A_lds[smp * AS * 4];

    // ---- own A row into registers
    f16v Ar0, Ar1;
    sfor<4>([&](auto J) {
        constexpr int j = decltype(J)::v;
        float4 v  = lds_a4(As, l, j);
        Ar0[4*j+0] = v.x;  Ar0[4*j+1] = v.y;  Ar0[4*j+2] = v.z;  Ar0[4*j+3] = v.w;
        float4 w4 = lds_a4(As, l, j + 4);
        Ar1[4*j+0] = w4.x; Ar1[4*j+1] = w4.y; Ar1[4*j+2] = w4.z; Ar1[4*j+3] = w4.w;
    });

    // ---- M = A A^T + jitter*I (row l)
    f16v Mrow, Vrow;
    sfor<16>([&](auto K) {
        constexpr int k = decltype(K)::v;
        float a0 = 0.f, a1 = 0.f, a2 = 0.f, a3 = 0.f;
        sfor<4>([&](auto J) {
            constexpr int j = decltype(J)::v;
            float4 v  = lds_a4(As, k, j);
            a0 += Ar0[4*j+0]*v.x;  a1 += Ar0[4*j+1]*v.y;
            a2 += Ar0[4*j+2]*v.z;  a3 += Ar0[4*j+3]*v.w;
            float4 w4 = lds_a4(As, k, j + 4);
            a0 += Ar1[4*j+0]*w4.x; a1 += Ar1[4*j+1]*w4.y;
            a2 += Ar1[4*j+2]*w4.z; a3 += Ar1[4*j+3]*w4.w;
        });
        Mrow[k] = (a0+a1)+(a2+a3) + ((k == l) ? kJitter : 0.f);
        Vrow[k] = (k == l) ? 1.f : 0.f;
    });

    // ---- triangular Gauss-Jordan inverse (SPD), width-16 shuffles
    sfor<16>([&](auto K) {
        constexpr int k = decltype(K)::v;
        float ip = 1.f / __shfl(Mrow[k], k, 16);
        float f  = (l == k) ? 0.f : Mrow[k] * ip;
        sfor<16>([&](auto J) {
            constexpr int j = decltype(J)::v;
            if constexpr (j > k) {
                float mj = __shfl(Mrow[j], k, 16);
                Mrow[j] = (l == k) ? mj * ip : Mrow[j] - f * mj;
            }
        });
        sfor<16>([&](auto J) {
            constexpr int j = decltype(J)::v;
            if constexpr (j < k) {
                float vj = __shfl(Vrow[j], k, 16);
                Vrow[j] = (l == k) ? vj * ip : Vrow[j] - f * vj;
            }
        });
        Vrow[k] = (l == k) ? ip : -f;
    });

    // ---- w = Minv b
    float w = 0.f;
    {
        float bval = bg[gs * MD + l];
        sfor<16>([&](auto K) {
            constexpr int k = decltype(K)::v;
            w += Vrow[k] * __shfl(bval, k, 16);
        });
    }

    // ---- C rows n0,n0+1 of A^T Minv via Vrow shuffles (no LDS buffer), fused with q = A^T w
    f16v Ca = (f16v)0.0f, Cb = (f16v)0.0f;
    float q0 = 0.f, q1 = 0.f;
    sfor<16>([&](auto K) {
        constexpr int k = decltype(K)::v;
        f2 ak = lds_a2(As, k, n0);
        float wm = __shfl(w, k, 16);
        q0 = fmaf(ak[0], wm, q0);
        q1 = fmaf(ak[1], wm, q1);
        sfor<16>([&](auto M) {
            constexpr int m = decltype(M)::v;
            float mv = __shfl(Vrow[m], k, 16);   // Minv[k][m]
            Ca[m] = fmaf(ak[0], mv, Ca[m]);
            Cb[m] = fmaf(ak[1], mv, Cb[m]);
        });
    });

    // ---- P in RING order: Qa_j = (P[2l][2cp], P[2l][2cp+1]), Qb_j = row 2l+1; cp=(l-j)&15.
    // Identity lands only in slot 0 (cp==l): Qa0[0] += 1, Qb0[1] += 1.
    constexpr float is = 1.f / kSigma;
#define QBUILD(j)                                                             \
    f2 Qa##j, Qb##j;                                                          \
    {                                                                         \
        const int n = 2 * ((l - (j)) & 15);                                   \
        float qa0 = 0.f, qa1 = 0.f, qb0 = 0.f, qb1 = 0.f;                     \
        sfor<16>([&](auto M) {                                                \
            constexpr int m = decltype(M)::v;                                 \
            f2 ak = lds_a2(As, m, n);                                         \
            qa0 = fmaf(Ca[m], ak[0], qa0); qa1 = fmaf(Ca[m], ak[1], qa1);     \
            qb0 = fmaf(Cb[m], ak[0], qb0); qb1 = fmaf(Cb[m], ak[1], qb1);     \
        });                                                                   \
        Qa##j[0] = ((((j) == 0) ? 1.f : 0.f) - qa0) * is;                     \
        Qa##j[1] = (0.f - qa1) * is;                                          \
        Qb##j[0] = (0.f - qb0) * is;                                          \
        Qb##j[1] = ((((j) == 0) ? 1.f : 0.f) - qb1) * is;                     \
    }
    QBUILD(0)  QBUILD(1)  QBUILD(2)  QBUILD(3)
    QBUILD(4)  QBUILD(5)  QBUILD(6)  QBUILD(7)
    QBUILD(8)  QBUILD(9)  QBUILD(10) QBUILD(11)
    QBUILD(12) QBUILD(13) QBUILD(14) QBUILD(15)
#undef QBUILD

    // ---- d = q - P c (ring order; one-time shuffles)
    float d0, d1;
    {
        f2 cpr = *reinterpret_cast<const f2*>(cg + gs * ND + n0);
        float pc0 = 0.f, pc1 = 0.f;
#define DSTEP(j) {                                                            \
        const int cp = (l - (j)) & 15;                                        \
        float c0 = __shfl(cpr[0], cp, 16);                                    \
        float c1 = __shfl(cpr[1], cp, 16);                                    \
        pc0 += Qa##j[0]*c0 + Qa##j[1]*c1;                                     \
        pc1 += Qb##j[0]*c0 + Qb##j[1]*c1; }
        DSTEP(0)  DSTEP(1)  DSTEP(2)  DSTEP(3)
        DSTEP(4)  DSTEP(5)  DSTEP(6)  DSTEP(7)
        DSTEP(8)  DSTEP(9)  DSTEP(10) DSTEP(11)
        DSTEP(12) DSTEP(13) DSTEP(14) DSTEP(15)
#undef DSTEP
        d0 = q0 - pc0;
        d1 = q1 - pc1;
    }

    // ================= Phase 2: 100 iterations, ZERO LDS, no barriers =================
    f2 lbv = *reinterpret_cast<const f2*>(lbg + gs * ND + n0);
    f2 ubv = *reinterpret_cast<const f2*>(ubg + gs * ND + n0);
    float lb0 = lbv[0], lb1 = lbv[1], ub0 = ubv[0], ub1 = ubv[1];
    float z0 = fminf(fmaxf(0.f, lb0), ub0);
    float z1 = fminf(fmaxf(0.f, lb1), ub1);
    float u0 = 0.f, u1 = 0.f, x0 = 0.f, x1 = 0.f;

    // acc += rotated(s) * q in ONE instruction: v_fmac_f32 with src0 DPP row_ror.
#define FSTEP(j)                                                              \
    asm("v_fmac_f32_dpp %0, %1, %2 row_ror:" #j " row_mask:0xf bank_mask:0xf" \
        : "+v"(ae) : "v"(s0), "v"(Qa##j[0]));                                 \
    asm("v_fmac_f32_dpp %0, %1, %2 row_ror:" #j " row_mask:0xf bank_mask:0xf" \
        : "+v"(ao) : "v"(s1), "v"(Qa##j[1]));                                 \
    asm("v_fmac_f32_dpp %0, %1, %2 row_ror:" #j " row_mask:0xf bank_mask:0xf" \
        : "+v"(be) : "v"(s0), "v"(Qb##j[0]));                                 \
    asm("v_fmac_f32_dpp %0, %1, %2 row_ror:" #j " row_mask:0xf bank_mask:0xf" \
        : "+v"(bo) : "v"(s1), "v"(Qb##j[1]));

    for (int it = 0; it < kIters; ++it) {
        float s0 = z0 - u0, s1 = z1 - u1;          // own column pair (rho == 1)
        float ae = d0, ao = 0.f, be = d1, bo = 0.f;
        // slot 0: s local, plain FMA
        ae = fmaf(Qa0[0], s0, ae); ao = fmaf(Qa0[1], s1, ao);
        be = fmaf(Qb0[0], s0, be); bo = fmaf(Qb0[1], s1, bo);
        FSTEP(1)  FSTEP(2)  FSTEP(3)  FSTEP(4)  FSTEP(5)
        FSTEP(6)  FSTEP(7)  FSTEP(8)  FSTEP(9)  FSTEP(10)
        FSTEP(11) FSTEP(12) FSTEP(13) FSTEP(14) FSTEP(15)
        x0 = ae + ao;
        x1 = be + bo;
        float t0 = x0 + u0, t1 = x1 + u1;
        z0 = fminf(fmaxf(t0, lb0), ub0);
        z1 = fminf(fmaxf(t1, lb1), ub1);
        u0 = t0 - z0;
        u1 = t1 - z1;
    }
#undef FSTEP

    f2 xo; xo[0] = x0; xo[1] = x1;
    *reinterpret_cast<f2*>(outg + gs * ND + n0) = xo;
}

extern "C" void kernel_launch(void* const* d_in, const int* in_sizes, int n_in,
                              void* d_out, int out_size, void* d_ws, size_t ws_size,
                              hipStream_t stream) {
    const float* A  = (const float*)d_in[0];
    const float* b  = (const float*)d_in[1];
    const float* c  = (const float*)d_in[2];
    const float* lb = (const float*)d_in[3];
    const float* ub = (const float*)d_in[4];
    float* out = (float*)d_out;
    const int B = in_sizes[1] / MD;      // 32768 samples
    admm_fused_kernel<<<B / SPA, 128, 0, stream>>>(A, b, c, lb, ub, out);
}